// Round 13
// baseline (81.911 us; speedup 1.0000x reference)
//
#include <hip/hip_runtime.h>
#include <hip/hip_bf16.h>

#define N_OBJ   32
#define G_TOTAL 4960      // C(32,3)
#define NPAIR   496       // C(32,2)
#define KTOT    1600      // 3*496 (pairs) + 3*32 (diag) + 16 pad
#define SEG01   0
#define SEG02   496
#define SEG12   992
#define SEGD0   1488
#define SEGD1   1520
#define SEGD2   1552
#define N_FILT  16
#define REL_D   16
#define BATCH   32
#define NQ      512
#define NIT2    25        // KTOT / 64

typedef __attribute__((ext_vector_type(8))) short bf16x8;
typedef __attribute__((ext_vector_type(4))) float f32x4;

static __device__ inline unsigned short f2bf(float x) {
    union { float f; unsigned int u; } v; v.f = x;
    unsigned int r = v.u + 0x7fffu + ((v.u >> 16) & 1u);   // RNE
    return (unsigned short)(r >> 16);
}
static __device__ inline void gload_lds16(const void* g, void* l) {
    __builtin_amdgcn_global_load_lds(
        (const __attribute__((address_space(1))) unsigned int*)g,
        (__attribute__((address_space(3))) unsigned int*)(unsigned int)(uintptr_t)l,
        16, 0, 0);
}
// base index of pairs starting with x in lexicographic C(32,2) packing
static __device__ inline int pbase(int x) { return (x * (63 - x)) >> 1; }
// unrank lexicographic 2-combination of 32
static __device__ inline void unrank2(int u, int& x, int& y) {
    for (x = 0; x < 31; x++) { int len = 31 - x; if (u < len) break; u -= len; }
    y = x + 1 + u;
}
static __device__ inline float dot16(float4 a0, float4 a1, float4 a2, float4 a3,
                                     const float* F) {
    float4 f0 = *(const float4*)(F);
    float4 f1 = *(const float4*)(F + 4);
    float4 f2 = *(const float4*)(F + 8);
    float4 f3 = *(const float4*)(F + 12);
    float d = a0.x * f0.x + a0.y * f0.y + a0.z * f0.z + a0.w * f0.w;
    d += a1.x * f1.x + a1.y * f1.y + a1.z * f1.z + a1.w * f1.w;
    d += a2.x * f2.x + a2.y * f2.y + a2.z * f2.z + a2.w * f2.w;
    d += a3.x * f3.x + a3.y * f3.y + a3.z * f3.z + a3.w * f3.w;
    return d;
}

// ===== L1: normw rows (0..511) + folded pairconv (512..583, 4 sub-blocks each) ====
__global__ __launch_bounds__(1024) void k_front(const float* __restrict__ logits,
                                                const float* __restrict__ inputs,
                                                const float* __restrict__ filters,
                                                unsigned short* __restrict__ Wp,
                                                unsigned short* __restrict__ Bp) {
    __shared__ __align__(16) char smem[11648];
    int t = threadIdx.x;
    int role = blockIdx.x;

    if (role < NQ) {
        float* sp  = (float*)smem;             // 32 floats
        float* red = (float*)(smem + 128);     // 8 floats
        float* Wf  = (float*)(smem + 192);     // 1600 floats
        int q = role;
        if (t < N_OBJ) {
            float x = logits[q * N_OBJ + t];
            float ex = __expf(x);
            sp[t] = (x > 15.f) ? x : __logf(1.f + ex);
        }
        __syncthreads();

        // pass A: 1488 independent range-sums, fully unrolled + predicated
#pragma unroll
        for (int rep = 0; rep < 2; rep++) {
            int idx = t + rep * 1024;
            if (idx < 3 * NPAIR) {
                int which = idx / NPAIR;
                int u = idx - which * NPAIR;
                int x, y; unrank2(u, x, y);
                float pxy = sp[x] * sp[y];
                int lo, hi;                          // include c with lo <= c < hi
                if (which == 0)      { lo = y + 1; hi = 32; }   // W01
                else if (which == 1) { lo = x + 1; hi = y;  }   // W02
                else                 { lo = 0;     hi = x;  }   // W12
                const float4* sp4 = (const float4*)sp;
                float s = 0.f;
#pragma unroll
                for (int cb = 0; cb < 8; cb++) {
                    float4 v = sp4[cb];
                    int c0 = cb * 4;
                    s += (c0 + 0 >= lo && c0 + 0 < hi) ? __expf(pxy * v.x) : 0.f;
                    s += (c0 + 1 >= lo && c0 + 1 < hi) ? __expf(pxy * v.y) : 0.f;
                    s += (c0 + 2 >= lo && c0 + 2 < hi) ? __expf(pxy * v.z) : 0.f;
                    s += (c0 + 3 >= lo && c0 + 3 < hi) ? __expf(pxy * v.w) : 0.f;
                }
                Wf[which * NPAIR + u] = s;
            }
        }
        __syncthreads();

        // stage 2 (parallel roles): reduce total | diag marginals | pad zero
        if (t < 512) {
            float lsum = (t < NPAIR) ? Wf[t] : 0.f;
#pragma unroll
            for (int off = 32; off; off >>= 1) lsum += __shfl_down(lsum, off, 64);
            if ((t & 63) == 0) red[t >> 6] = lsum;
        } else if (t < 608) {
            int which = (t - 512) >> 5, idx = t & 31;
            float s = 0.f;
            if (which == 0) {                        // Wd0[a] = sum_{b>a} W01[a,b]
                int base = pbase(idx);
                for (int u = idx + 1; u < 32; u++) s += Wf[SEG01 + base + u - idx - 1];
                Wf[SEGD0 + idx] = s;
            } else if (which == 1) {                 // Wd1[b] = sum_{a<b} W01[a,b]
                for (int a2 = 0; a2 < idx; a2++) s += Wf[SEG01 + pbase(a2) + idx - a2 - 1];
                Wf[SEGD1 + idx] = s;
            } else {                                 // Wd2[c] = sum_{b<c} W12[b,c]
                for (int b2 = 0; b2 < idx; b2++) s += Wf[SEG12 + pbase(b2) + idx - b2 - 1];
                Wf[SEGD2 + idx] = s;
            }
        } else if (t < 624) {
            Wf[1584 + (t - 608)] = 0.f;              // K-pad
        }
        __syncthreads();

        // stage 3: normalize + pack + coalesced row write (800 uints)
        if (t < KTOT / 2) {
            float total = red[0] + red[1] + red[2] + red[3] +
                          red[4] + red[5] + red[6] + red[7];
            float inv = 1.f / total;
            unsigned int pk = (unsigned int)f2bf(Wf[2 * t] * inv) |
                              ((unsigned int)f2bf(Wf[2 * t + 1] * inv) << 16);
            ((unsigned int*)(Wp + (size_t)q * KTOT))[t] = pk;
        }
    } else {
        // ---------- folded pairconv: block covers 4 of the 256-thread work units ---
        float* flt = (float*)smem;            // 16*180 floats = 11520 B
        int role2 = role - NQ;                // 0..71
        if (t < 576) {
            int i4 = t * 4;
            int f = i4 / 144;
            int r = i4 - f * 144;
            *(float4*)&flt[f * 180 + (r >> 4) * 20 + (r & 15)] = *(const float4*)(filters + i4);
        }
        __syncthreads();

        int oldbid = role2 * 4 + (t >> 8);    // 0..287
        int tp = t & 255;
        int b = oldbid / 9, ch = oldbid - b * 9;
        int lane = tp & 63, fq = tp >> 6;     // 4 filter-quads x 64 items
        int u = ch * 64 + lane;
        if (u < NPAIR) {
            int x, y; unrank2(u, x, y);
            const float4* rxy = (const float4*)(inputs + (((size_t)b * 32 + x) * 32 + y) * 16);
            const float4* ryx = (const float4*)(inputs + (((size_t)b * 32 + y) * 32 + x) * 16);
            float4 a0 = rxy[0], a1 = rxy[1], a2 = rxy[2], a3 = rxy[3];
            float4 c0 = ryx[0], c1 = ryx[1], c2 = ryx[2], c3 = ryx[3];
#pragma unroll
            for (int fi = 0; fi < 4; fi++) {
                const float* F = &flt[(fq * 4 + fi) * 180];
                float v01 = dot16(a0, a1, a2, a3, F + 1 * 20) + dot16(c0, c1, c2, c3, F + 3 * 20);
                float v02 = dot16(a0, a1, a2, a3, F + 2 * 20) + dot16(c0, c1, c2, c3, F + 6 * 20);
                float v12 = dot16(a0, a1, a2, a3, F + 5 * 20) + dot16(c0, c1, c2, c3, F + 7 * 20);
                size_t nrow = ((size_t)b * 16 + fq * 4 + fi) * KTOT;
                Bp[nrow + SEG01 + u] = f2bf(v01);
                Bp[nrow + SEG02 + u] = f2bf(v02);
                Bp[nrow + SEG12 + u] = f2bf(v12);
            }
        } else if (u < 528) {
            int x = u - NPAIR;                // diagonal element
            const float4* rxx = (const float4*)(inputs + (((size_t)b * 32 + x) * 32 + x) * 16);
            float4 a0 = rxx[0], a1 = rxx[1], a2 = rxx[2], a3 = rxx[3];
#pragma unroll
            for (int fi = 0; fi < 4; fi++) {
                const float* F = &flt[(fq * 4 + fi) * 180];
                float v0 = dot16(a0, a1, a2, a3, F + 0 * 20);
                float v4 = dot16(a0, a1, a2, a3, F + 4 * 20);
                float v8 = dot16(a0, a1, a2, a3, F + 8 * 20);
                size_t nrow = ((size_t)b * 16 + fq * 4 + fi) * KTOT;
                Bp[nrow + SEGD0 + x] = f2bf(v0);
                Bp[nrow + SEGD1 + x] = f2bf(v4);
                Bp[nrow + SEGD2 + x] = f2bf(v8);
            }
        } else if (ch == 8 && lane >= 16 && lane < 32) {
            int col = lane - 16;              // zero K-pad cols 1584..1599
#pragma unroll
            for (int fi = 0; fi < 4; fi++)
                Bp[((size_t)b * 16 + fq * 4 + fi) * KTOT + 1584 + col] = 0;
        }
    }
}

// ===== L2: out = Wp(512xK) x Bp^T — full-K, 256 blocks of 32x32, direct write =====
__global__ __launch_bounds__(256) void k_gemm(const unsigned short* __restrict__ A,
                                              const unsigned short* __restrict__ Bm,
                                              float* __restrict__ out) {
    __shared__ __align__(16) unsigned short As[2][32 * 64];
    __shared__ __align__(16) unsigned short Bs[2][32 * 64];
    int tid = threadIdx.x;
    int q0 = blockIdx.x * 32, n0 = blockIdx.y * 32;
    int wave = tid >> 6, lane = tid & 63;
    int wm = wave & 1, wn = wave >> 1;
    int row16 = lane & 15, quad = lane >> 4;

    // staging: thread t -> row t>>3 (0..31), 16B chunk (t&7) XOR-swizzled on the
    // GLOBAL side (gload_lds writes LDS linearly: base + tid*16)
    int srow = tid >> 3;
    int schunk = (tid & 7) ^ ((srow >> 1) & 7);
    const unsigned short* ga = A + (size_t)(q0 + srow) * KTOT + schunk * 8;
    const unsigned short* gb = Bm + (size_t)(n0 + srow) * KTOT + schunk * 8;
    char* lA = (char*)&As[0][0] + tid * 16;
    char* lB = (char*)&Bs[0][0] + tid * 16;

    f32x4 acc = {};
    int xk = (row16 >> 1) & 7;

    gload_lds16(ga, lA);
    gload_lds16(gb, lB);
    for (int it = 0; it < NIT2; ++it) {
        __syncthreads();
        if (it + 1 < NIT2) {
            int nb = (it + 1) & 1;
            gload_lds16(ga + (it + 1) * 64, lA + nb * 32 * 64 * 2);
            gload_lds16(gb + (it + 1) * 64, lB + nb * 32 * 64 * 2);
        }
        int buf = it & 1;
#pragma unroll
        for (int ks = 0; ks < 2; ks++) {
            int ca = (((ks * 4) + quad) ^ xk) * 8;   // un-swizzle to global chunk
            bf16x8 afr = *(const bf16x8*)&As[buf][(wm * 16 + row16) * 64 + ca];
            bf16x8 bfr = *(const bf16x8*)&Bs[buf][(wn * 16 + row16) * 64 + ca];
            acc = __builtin_amdgcn_mfma_f32_16x16x32_bf16(afr, bfr, acc, 0, 0, 0);
        }
    }

    // epilogue: n = n0 + wn*16 + row16 -> b constant per wave, f = row16
    int bq = (n0 + wn * 16) >> 4;
    float* o = out + (size_t)bq * (NQ * REL_D) + row16;
#pragma unroll
    for (int r = 0; r < 4; r++) {
        int q = q0 + wm * 16 + quad * 4 + r;
        o[q * REL_D] = acc[r];
    }
}

extern "C" void kernel_launch(void* const* d_in, const int* in_sizes, int n_in,
                              void* d_out, int out_size, void* d_ws, size_t ws_size,
                              hipStream_t stream) {
    const float* inputs  = (const float*)d_in[0];   // (32,32,32,16)
    const float* logits  = (const float*)d_in[1];   // (512,32)
    const float* filters = (const float*)d_in[2];   // (16,3,3,16)
    float* out = (float*)d_out;                     // (32,512,16)

    char* ws = (char*)d_ws;
    unsigned short* Wp = (unsigned short*)ws;                    // 1,638,400 B
    unsigned short* Bp = (unsigned short*)(ws + 1638400);        // 1,638,400 B

    k_front<<<NQ + 72, 1024, 0, stream>>>(logits, inputs, filters, Wp, Bp);
    k_gemm<<<dim3(16, 16), 256, 0, stream>>>(Wp, Bp, out);
}